// Round 3
// baseline (1444.103 us; speedup 1.0000x reference)
//
#include <hip/hip_runtime.h>
#include <stdint.h>

typedef unsigned short u16;
typedef unsigned int u32;
typedef short bf16x8 __attribute__((ext_vector_type(8)));
typedef float f32x4 __attribute__((ext_vector_type(4)));

__device__ __forceinline__ float bf2f(u16 h) {
  union { u32 u; float f; } v; v.u = ((u32)h) << 16; return v.f;
}
__device__ __forceinline__ u16 f2bf(float f) {
  union { float f; u32 u; } v; v.f = f;
  return (u16)((v.u + 0x7FFFu + ((v.u >> 16) & 1u)) >> 16);
}
// NaN/inf scrub with stage marker: keeps failures finite + localizable.
__device__ __forceinline__ float scrub(float v, float mark) {
  return (v == v && fabsf(v) < 1e30f) ? v : mark;
}

// -------------------------------------------------------------- detector ---
// Decide whether d_in holds bf16 (u16 stream) or fp32. Sample 1024 even-index
// u16s of hidden_states: bf16 N(0,1) data -> exponent field sane (~100%);
// fp32 data -> even u16s are mantissa-low garbage (~18% sane). flag: 1=fp32.
__global__ __launch_bounds__(256) void detect_kernel(const u16* __restrict__ hs, int* flagp) {
  __shared__ int cnt;
  if (threadIdx.x == 0) cnt = 0;
  __syncthreads();
  int sane = 0;
  #pragma unroll
  for (int j = 0; j < 4; j++) {
    const u16 v = hs[(threadIdx.x * 4 + j) * 2];
    const int e = (v >> 7) & 0xFF;
    sane += (e >= 0x60 && e <= 0x8E) ? 1 : 0;
  }
  atomicAdd(&cnt, sane);
  __syncthreads();
  if (threadIdx.x == 0) *flagp = (cnt < 600) ? 1 : 0;
}

// ------------------------------------------------------------- converter ---
// dst (bf16) <- src (fp32 if *flagp else bf16). 4 elems/thread.
__global__ __launch_bounds__(256) void convert_kernel(
    const void* __restrict__ src, u16* __restrict__ dst, int n, const int* __restrict__ flagp) {
  const int f = *flagp;
  const int i = (blockIdx.x * 256 + threadIdx.x) * 4;
  if (i >= n) return;
  union { uint2 u; u16 s[4]; } o;
  if (f) {
    const float4 v = *(const float4*)((const float*)src + i);
    o.s[0] = f2bf(v.x); o.s[1] = f2bf(v.y); o.s[2] = f2bf(v.z); o.s[3] = f2bf(v.w);
  } else {
    o.u = *(const uint2*)((const u16*)src + i);
  }
  *(uint2*)(dst + i) = o.u;
}

// ---------------------------------------------------------------- RMSNorm ---
__global__ __launch_bounds__(256) void rmsnorm_kernel(
    const u16* __restrict__ xin, const u16* __restrict__ w, u16* __restrict__ out)
{
  __shared__ float red[4];
  const int row = blockIdx.x, tid = threadIdx.x;
  const u16* xr = xin + (size_t)row * 2048 + tid * 8;
  union { uint4 q; u16 s[8]; } uu; uu.q = *(const uint4*)xr;
  float v[8];
  #pragma unroll
  for (int j = 0; j < 8; j++) v[j] = bf2f(uu.s[j]);
  float ss = 0.f;
  #pragma unroll
  for (int j = 0; j < 8; j++) ss += v[j] * v[j];
  #pragma unroll
  for (int o = 32; o; o >>= 1) ss += __shfl_xor(ss, o, 64);
  if ((tid & 63) == 0) red[tid >> 6] = ss;
  __syncthreads();
  float rstd = rsqrtf((red[0] + red[1] + red[2] + red[3]) * (1.0f / 2048.0f) + 1e-5f);
  rstd = bf2f(f2bf(rstd));  // reference casts rstd to bf16
  union { uint4 q; u16 s[8]; } ww; ww.q = *(const uint4*)(w + tid * 8);
  union { uint4 q; u16 s[8]; } oo;
  #pragma unroll
  for (int j = 0; j < 8; j++) oo.s[j] = f2bf(scrub(v[j] * rstd * bf2f(ww.s[j]), 200.f));
  *(uint4*)(out + (size_t)row * 2048 + tid * 8) = oo.q;
}

// -------------------------------------------------------------- transpose ---
// out[c*R + r] = in[r*C + c]; in is fp32 if *flagp else bf16. grid (C/32,R/32)
__global__ __launch_bounds__(256) void transpose_kernel(
    const void* __restrict__ in, u16* __restrict__ out, int R, int C,
    const int* __restrict__ flagp)
{
  __shared__ u16 tile[32][33];
  const int f = *flagp;
  const int tx = threadIdx.x, ty = threadIdx.y;
  const int x = blockIdx.x * 32 + tx;
  const int y0 = blockIdx.y * 32;
  if (f) {
    #pragma unroll
    for (int j = ty; j < 32; j += 8) tile[j][tx] = f2bf(((const float*)in)[(size_t)(y0 + j) * C + x]);
  } else {
    #pragma unroll
    for (int j = ty; j < 32; j += 8) tile[j][tx] = ((const u16*)in)[(size_t)(y0 + j) * C + x];
  }
  __syncthreads();
  const int xo = y0 + tx, yo0 = blockIdx.x * 32;
  #pragma unroll
  for (int j = ty; j < 32; j += 8) out[(size_t)(yo0 + j) * R + xo] = tile[tx][j];
}

// ------------------------------------------------------------------- GEMM ---
// C[M,N] = A[M,K] @ Bt[N,K]^T, bf16 in, fp32 accum. 128x128 tile, BK=32,
// 256 threads (2x2 waves of 64x64). Register-staged LDS; LDS pos p of row r
// holds global chunk p ^ ((r>>1)&3); read at p = quad ^ ((r>>1)&3).
enum { EPI_STORE = 0, EPI_ADD = 1, EPI_SILU = 2, EPI_ADD_OUT = 3 };

template<int EPI>
__global__ __launch_bounds__(256, 2) void gemm_bt_kernel(
    const u16* __restrict__ A, const u16* __restrict__ Bt,
    void* Cout, const void* aux, int M, int N, int K,
    const int* __restrict__ flagp)
{
  __shared__ alignas(16) u16 As[128 * 32];
  __shared__ alignas(16) u16 Bs[128 * 32];
  const int tid = threadIdx.x;
  const int wid = tid >> 6, lane = tid & 63;
  const int lrow = lane & 15, quad = lane >> 4;
  const int m0 = blockIdx.y * 128, n0 = blockIdx.x * 128;
  const int wm = (wid >> 1) * 64, wn = (wid & 1) * 64;

  const int r0 = tid >> 2, p0 = tid & 3, g0 = p0 ^ ((r0 >> 1) & 3);
  const int r1 = 64 + (tid >> 2), g1 = p0 ^ ((r1 >> 1) & 3);
  const int lp0 = r0 * 32 + p0 * 8, lp1 = r1 * 32 + p0 * 8;

  const u16* Ar0 = A + (size_t)(m0 + r0) * K + g0 * 8;
  const u16* Ar1 = A + (size_t)(m0 + r1) * K + g1 * 8;
  const u16* Br0 = Bt + (size_t)(n0 + r0) * K + g0 * 8;
  const u16* Br1 = Bt + (size_t)(n0 + r1) * K + g1 * 8;

  f32x4 acc[4][4] = {};

  for (int k0 = 0; k0 < K; k0 += 32) {
    const uint4 a0 = *(const uint4*)(Ar0 + k0);
    const uint4 a1 = *(const uint4*)(Ar1 + k0);
    const uint4 b0 = *(const uint4*)(Br0 + k0);
    const uint4 b1 = *(const uint4*)(Br1 + k0);
    __syncthreads();
    *(uint4*)&As[lp0] = a0;
    *(uint4*)&As[lp1] = a1;
    *(uint4*)&Bs[lp0] = b0;
    *(uint4*)&Bs[lp1] = b1;
    __syncthreads();

    bf16x8 af[4], bfm[4];
    #pragma unroll
    for (int mt = 0; mt < 4; mt++) {
      int r = wm + mt * 16 + lrow;
      int p = quad ^ ((r >> 1) & 3);
      af[mt] = *(const bf16x8*)&As[r * 32 + p * 8];
    }
    #pragma unroll
    for (int nt = 0; nt < 4; nt++) {
      int r = wn + nt * 16 + lrow;
      int p = quad ^ ((r >> 1) & 3);
      bfm[nt] = *(const bf16x8*)&Bs[r * 32 + p * 8];
    }
    #pragma unroll
    for (int mt = 0; mt < 4; mt++)
      #pragma unroll
      for (int nt = 0; nt < 4; nt++)
        acc[mt][nt] = __builtin_amdgcn_mfma_f32_16x16x32_bf16(af[mt], bfm[nt], acc[mt][nt], 0, 0, 0);
  }

  const int oflag = (EPI == EPI_ADD_OUT) ? *flagp : 0;
  #pragma unroll
  for (int mt = 0; mt < 4; mt++)
    #pragma unroll
    for (int nt = 0; nt < 4; nt++)
      #pragma unroll
      for (int i = 0; i < 4; i++) {
        const int row = m0 + wm + mt * 16 + quad * 4 + i;
        const int col = n0 + wn + nt * 16 + lrow;
        const size_t idx = (size_t)row * N + col;
        const float vv = acc[mt][nt][i];
        if (EPI == EPI_STORE) {
          ((u16*)Cout)[idx] = f2bf(scrub(vv, 300.f));
        } else if (EPI == EPI_ADD) {
          ((u16*)Cout)[idx] = f2bf(scrub(bf2f(((const u16*)aux)[idx]) + vv, 700.f));
        } else if (EPI == EPI_SILU) {
          float g = bf2f(((const u16*)aux)[idx]);
          g = fminf(fmaxf(g, -30.f), 30.f);
          const float s = g / (1.0f + __expf(-g));
          ((u16*)Cout)[idx] = f2bf(scrub(s * vv, 800.f));
        } else {  // EPI_ADD_OUT: residual add, dtype-flagged final store
          const float r = scrub(bf2f(((const u16*)aux)[idx]) + vv, 1e6f);
          if (oflag) ((float*)Cout)[idx] = r;
          else       ((u16*)Cout)[idx] = f2bf(r);
        }
      }
}

// ------------------------------------------------------------------- RoPE ---
// in-place on fused qkv [4096 tok][4096]; heads 0..15=q, 16..23=k.
__global__ __launch_bounds__(256) void rope_kernel(
    u16* qkv, const u16* __restrict__ cosb, const u16* __restrict__ sinb)
{
  const int gw = blockIdx.x * 4 + (threadIdx.x >> 6);
  const int lane = threadIdx.x & 63;
  const int h = gw % 24;
  const int t = gw / 24;
  u16* base = qkv + (size_t)t * 4096 + h * 128;
  const u32 x01 = *(const u32*)(base + 2 * lane);
  const float x1 = bf2f((u16)(x01 & 0xffff));
  const float x2 = bf2f((u16)(x01 >> 16));
  const float c = bf2f(cosb[t * 64 + lane]);
  const float s = bf2f(sinb[t * 64 + lane]);
  const u16 o1 = f2bf(x1 * c - x2 * s);
  const u16 o2 = f2bf(x1 * s + x2 * c);
  base[lane] = o1;
  base[64 + lane] = o2;
}

// ------------------------------------------------------------ flash attn ---
__global__ __launch_bounds__(256, 2) void flash_attn_kernel(
    const u16* __restrict__ qkv, const u16* __restrict__ mask, u16* __restrict__ obuf)
{
  __shared__ alignas(16) u16 Kt[64 * 128];
  __shared__ alignas(16) u16 Vt[128 * 64];
  __shared__ alignas(16) u16 Ps[4 * 16 * 64];

  const int qt = blockIdx.x, h = blockIdx.y, b = blockIdx.z;
  const int tid = threadIdx.x;
  const int wid = tid >> 6, lane = tid & 63;
  const int lrow = lane & 15, quad = lane >> 4;
  const int kvh = h >> 1;
  const size_t tok0 = (size_t)b * 2048;

  bf16x8 qf[4];
  {
    const u16* qptr = qkv + (tok0 + qt * 64 + wid * 16 + lrow) * 4096 + h * 128 + quad * 8;
    #pragma unroll
    for (int kk = 0; kk < 4; kk++) qf[kk] = *(const bf16x8*)(qptr + kk * 32);
  }
  const u16* kbase = qkv + tok0 * 4096 + 2048 + kvh * 128;
  const u16* vbase = qkv + tok0 * 4096 + 3072 + kvh * 128;
  const u16* mbase = mask + (tok0 + qt * 64 + wid * 16) * 2048;

  float mst[4] = {-1e30f, -1e30f, -1e30f, -1e30f};
  float lst[4] = {0.f, 0.f, 0.f, 0.f};
  f32x4 oacc[8] = {};
  const float scale = 0.08838834764831845f;  // 1/sqrt(128)

  for (int kt = 0; kt < 32; kt++) {
    __syncthreads();
    #pragma unroll
    for (int cc = 0; cc < 4; cc++) {
      const int ci = cc * 256 + tid;
      const int r = ci >> 4, p = ci & 15;
      const int g = p ^ (r & 7);
      *(uint4*)&Kt[r * 128 + p * 8] =
          *(const uint4*)(kbase + (size_t)(kt * 64 + r) * 4096 + g * 8);
    }
    {
      const int kp = tid & 31, dg = tid >> 5;
      const u16* gv = vbase + (size_t)(kt * 64 + 2 * kp) * 4096 + dg * 16;
      union { uint4 q[2]; u16 s[16]; } r0, r1;
      r0.q[0] = *(const uint4*)gv;          r0.q[1] = *(const uint4*)(gv + 8);
      r1.q[0] = *(const uint4*)(gv + 4096); r1.q[1] = *(const uint4*)(gv + 4096 + 8);
      #pragma unroll
      for (int dd = 0; dd < 16; dd++) {
        const int d = dg * 16 + dd;
        const int word = (((kp >> 2) ^ (d & 7)) << 2) | (kp & 3);
        *(u32*)&Vt[d * 64 + word * 2] = (u32)r0.s[dd] | ((u32)r1.s[dd] << 16);
      }
    }
    __syncthreads();

    f32x4 sfr[4] = {};
    #pragma unroll
    for (int nt = 0; nt < 4; nt++) {
      const int r = nt * 16 + lrow;
      #pragma unroll
      for (int kk = 0; kk < 4; kk++) {
        bf16x8 kf = *(const bf16x8*)&Kt[r * 128 + (((kk * 4 + quad) ^ (r & 7)) << 3)];
        sfr[nt] = __builtin_amdgcn_mfma_f32_16x16x32_bf16(qf[kk], kf, sfr[nt], 0, 0, 0);
      }
    }
    #pragma unroll
    for (int nt = 0; nt < 4; nt++)
      #pragma unroll
      for (int i = 0; i < 4; i++) {
        const float mv = bf2f(mbase[(size_t)(quad * 4 + i) * 2048 + kt * 64 + nt * 16 + lrow]);
        sfr[nt][i] = fminf(fmaxf(sfr[nt][i] * scale + mv, -1e4f), 1e4f);
      }
    float alpha[4], mnew[4], rsum[4];
    #pragma unroll
    for (int i = 0; i < 4; i++) {
      float mx = fmaxf(fmaxf(sfr[0][i], sfr[1][i]), fmaxf(sfr[2][i], sfr[3][i]));
      #pragma unroll
      for (int o = 8; o; o >>= 1) mx = fmaxf(mx, __shfl_xor(mx, o, 64));
      mnew[i] = fmaxf(mst[i], mx);
      alpha[i] = __expf(mst[i] - mnew[i]);
      mst[i] = mnew[i];
      rsum[i] = 0.f;
    }
    #pragma unroll
    for (int nt = 0; nt < 4; nt++)
      #pragma unroll
      for (int i = 0; i < 4; i++) {
        const float p = __expf(sfr[nt][i] - mnew[i]);
        rsum[i] += p;
        Ps[wid * 1024 + (quad * 4 + i) * 64 + nt * 16 + lrow] = f2bf(p);
      }
    #pragma unroll
    for (int i = 0; i < 4; i++) {
      #pragma unroll
      for (int o = 8; o; o >>= 1) rsum[i] += __shfl_xor(rsum[i], o, 64);
      lst[i] = lst[i] * alpha[i] + rsum[i];
    }
    #pragma unroll
    for (int dt = 0; dt < 8; dt++)
      #pragma unroll
      for (int i = 0; i < 4; i++) oacc[dt][i] *= alpha[i];

    asm volatile("s_waitcnt lgkmcnt(0)" ::: "memory");
    #pragma unroll
    for (int kk = 0; kk < 2; kk++) {
      bf16x8 pf = *(const bf16x8*)&Ps[wid * 1024 + lrow * 64 + kk * 32 + quad * 8];
      #pragma unroll
      for (int dt = 0; dt < 8; dt++) {
        const int d = dt * 16 + lrow;
        bf16x8 vf = *(const bf16x8*)&Vt[d * 64 + (((kk * 4 + quad) ^ (d & 7)) << 3)];
        oacc[dt] = __builtin_amdgcn_mfma_f32_16x16x32_bf16(pf, vf, oacc[dt], 0, 0, 0);
      }
    }
  }

  #pragma unroll
  for (int dt = 0; dt < 8; dt++)
    #pragma unroll
    for (int i = 0; i < 4; i++) {
      const size_t tok = tok0 + qt * 64 + wid * 16 + quad * 4 + i;
      obuf[tok * 2048 + h * 128 + dt * 16 + lrow] = f2bf(scrub(oacc[dt][i] / lst[i], 500.f));
    }
}

// ----------------------------------------------------------------- launch ---
extern "C" void kernel_launch(void* const* d_in, const int* in_sizes, int n_in,
                              void* d_out, int out_size, void* d_ws, size_t ws_size,
                              hipStream_t stream) {
  (void)in_sizes; (void)n_in; (void)out_size; (void)ws_size;
  const void* hs   = d_in[0];
  const void* cosi = d_in[1];
  const void* sini = d_in[2];
  const void* mask = d_in[3];
  const void* wq   = d_in[4];
  const void* wk   = d_in[5];
  const void* wv   = d_in[6];
  const void* wo   = d_in[7];
  const void* wg   = d_in[8];
  const void* wu   = d_in[9];
  const void* wd   = d_in[10];
  const void* ln1  = d_in[11];
  const void* ln2  = d_in[12];

  char* ws = (char*)d_ws;                          // 178 MB total
  int* flag  = (int*)ws;                           // 16 B
  u16* ln1b  = (u16*)(ws + 4096);                  // 4 KB
  u16* ln2b  = (u16*)(ws + 16384);                 // 4 KB
  u16* cosb  = (u16*)(ws + (1u << 20));            // 0.5 MB
  u16* sinb  = (u16*)(ws + (1u << 20) + (1u << 19));
  u16* hsb   = (u16*)(ws + (2u  << 20));           // 16 MB bf16 hidden_states
  u16* xn    = (u16*)(ws + (18u << 20));           // 16 MB normed x; later h2
  u16* qkv   = (u16*)(ws + (34u << 20));           // 32 MB fused q|k|v
  u16* abuf  = (u16*)(ws + (66u << 20));           // 16 MB attention out
  u16* wT    = (u16*)(ws + (82u << 20));           // 32 MB transposed weights
  u16* gbuf  = (u16*)(ws + (114u << 20));          // 64 MB gate/h
  u16* maskb = (u16*)(ws + (114u << 20));          // 16 MB (dead before gbuf written)
  u16* x2n   = hsb;                                // hsb dead after O-proj
  u16* h2    = xn;                                 // xn dead after QKV gemm

  dim3 tb(32, 8);
  detect_kernel<<<1, 256, 0, stream>>>((const u16*)hs, flag);
  // bf16 input arena
  convert_kernel<<<8192, 256, 0, stream>>>(hs,   hsb,   8388608, flag);
  convert_kernel<<<256,  256, 0, stream>>>(cosi, cosb,  262144,  flag);
  convert_kernel<<<256,  256, 0, stream>>>(sini, sinb,  262144,  flag);
  convert_kernel<<<8192, 256, 0, stream>>>(mask, maskb, 8388608, flag);
  convert_kernel<<<2,    256, 0, stream>>>(ln1,  ln1b,  2048,    flag);
  convert_kernel<<<2,    256, 0, stream>>>(ln2,  ln2b,  2048,    flag);
  // LN1
  rmsnorm_kernel<<<4096, 256, 0, stream>>>(hsb, ln1b, xn);
  // fused QKV weights: wq^T | wk^T | wv^T stacked as [4096][2048]
  transpose_kernel<<<dim3(64, 64), tb, 0, stream>>>(wq, wT, 2048, 2048, flag);
  transpose_kernel<<<dim3(32, 64), tb, 0, stream>>>(wk, wT + (size_t)2048 * 2048, 2048, 1024, flag);
  transpose_kernel<<<dim3(32, 64), tb, 0, stream>>>(wv, wT + (size_t)3072 * 2048, 2048, 1024, flag);
  gemm_bt_kernel<EPI_STORE><<<dim3(32, 32), 256, 0, stream>>>(xn, wT, qkv, nullptr, 4096, 4096, 2048, flag);
  // RoPE on q and k heads
  rope_kernel<<<24576, 256, 0, stream>>>(qkv, cosb, sinb);
  // attention
  flash_attn_kernel<<<dim3(32, 16, 2), 256, 0, stream>>>(qkv, maskb, abuf);
  // O proj + residual -> h2
  transpose_kernel<<<dim3(64, 64), tb, 0, stream>>>(wo, wT, 2048, 2048, flag);
  gemm_bt_kernel<EPI_ADD><<<dim3(16, 32), 256, 0, stream>>>(abuf, wT, h2, hsb, 4096, 2048, 2048, flag);
  // LN2
  rmsnorm_kernel<<<4096, 256, 0, stream>>>(h2, ln2b, x2n);
  // MLP
  transpose_kernel<<<dim3(256, 64), tb, 0, stream>>>(wg, wT, 2048, 8192, flag);
  gemm_bt_kernel<EPI_STORE><<<dim3(64, 32), 256, 0, stream>>>(x2n, wT, gbuf, nullptr, 4096, 8192, 2048, flag);
  transpose_kernel<<<dim3(256, 64), tb, 0, stream>>>(wu, wT, 2048, 8192, flag);
  gemm_bt_kernel<EPI_SILU><<<dim3(64, 32), 256, 0, stream>>>(x2n, wT, gbuf, gbuf, 4096, 8192, 2048, flag);
  transpose_kernel<<<dim3(64, 256), tb, 0, stream>>>(wd, wT, 8192, 2048, flag);
  gemm_bt_kernel<EPI_ADD_OUT><<<dim3(16, 32), 256, 0, stream>>>(gbuf, wT, d_out, h2, 4096, 2048, 8192, flag);
}

// Round 4
// 1239.783 us; speedup vs baseline: 1.1648x; 1.1648x over previous
//
#include <hip/hip_runtime.h>
#include <stdint.h>

typedef unsigned short u16;
typedef unsigned int u32;
typedef short bf16x8 __attribute__((ext_vector_type(8)));
typedef float f32x4 __attribute__((ext_vector_type(4)));

#define AS_GLOBAL __attribute__((address_space(1)))
#define AS_LDS    __attribute__((address_space(3)))

__device__ __forceinline__ float bf2f(u16 h) {
  union { u32 u; float f; } v; v.u = ((u32)h) << 16; return v.f;
}
__device__ __forceinline__ u16 f2bf(float f) {
  union { float f; u32 u; } v; v.f = f;
  return (u16)((v.u + 0x7FFFu + ((v.u >> 16) & 1u)) >> 16);
}
__device__ __forceinline__ float scrub(float v, float mark) {
  return (v == v && fabsf(v) < 1e30f) ? v : mark;
}
// async global->LDS, 16B/lane; LDS dest = wave-uniform base + lane*16.
__device__ __forceinline__ void gload16(const void* g, void* l) {
  __builtin_amdgcn_global_load_lds((const AS_GLOBAL u32*)g, (AS_LDS u32*)l, 16, 0, 0);
}

// -------------------------------------------------------------- detectors ---
// dtype: sample even-index u16s of hidden_states; bf16 -> sane exponents.
__global__ __launch_bounds__(256) void detect_kernel(const u16* __restrict__ hs, int* flagp) {
  __shared__ int cnt;
  if (threadIdx.x == 0) cnt = 0;
  __syncthreads();
  int sane = 0;
  #pragma unroll
  for (int j = 0; j < 4; j++) {
    const u16 v = hs[(threadIdx.x * 4 + j) * 2];
    const int e = (v >> 7) & 0xFF;
    sane += (e >= 0x60 && e <= 0x8E) ? 1 : 0;
  }
  atomicAdd(&cnt, sane);
  __syncthreads();
  if (threadIdx.x == 0) *flagp = (cnt < 600) ? 1 : 0;
}

__global__ void init_flag2_kernel(int* flag2p) { *flag2p = 0; }

// set flag2=1 if any nonzero bits in mask (size n elems; width per *flagp).
__global__ __launch_bounds__(256) void detect_mask_kernel(
    const void* __restrict__ mask, int n, const int* __restrict__ flagp, int* flag2p) {
  const int f = *flagp;
  const size_t nq = (size_t)n * (f ? 4 : 2) / 16;  // # uint4
  u32 acc = 0;
  for (size_t i = blockIdx.x * 256 + threadIdx.x; i < nq; i += (size_t)gridDim.x * 256) {
    const uint4 v = ((const uint4*)mask)[i];
    acc |= v.x | v.y | v.z | v.w;
  }
  if (__ballot(acc != 0) != 0ull && (threadIdx.x & 63) == 0)
    atomicOr(flag2p, 1);
}

// ------------------------------------------------------------- converter ---
__global__ __launch_bounds__(256) void convert_kernel(
    const void* __restrict__ src, u16* __restrict__ dst, int n, const int* __restrict__ flagp) {
  const int f = *flagp;
  const int i = (blockIdx.x * 256 + threadIdx.x) * 4;
  if (i >= n) return;
  union { uint2 u; u16 s[4]; } o;
  if (f) {
    const float4 v = *(const float4*)((const float*)src + i);
    o.s[0] = f2bf(v.x); o.s[1] = f2bf(v.y); o.s[2] = f2bf(v.z); o.s[3] = f2bf(v.w);
  } else {
    o.u = *(const uint2*)((const u16*)src + i);
  }
  *(uint2*)(dst + i) = o.u;
}

// ---------------------------------------------------------------- RMSNorm ---
__global__ __launch_bounds__(256) void rmsnorm_kernel(
    const u16* __restrict__ xin, const u16* __restrict__ w, u16* __restrict__ out)
{
  __shared__ float red[4];
  const int row = blockIdx.x, tid = threadIdx.x;
  const u16* xr = xin + (size_t)row * 2048 + tid * 8;
  union { uint4 q; u16 s[8]; } uu; uu.q = *(const uint4*)xr;
  float v[8];
  #pragma unroll
  for (int j = 0; j < 8; j++) v[j] = bf2f(uu.s[j]);
  float ss = 0.f;
  #pragma unroll
  for (int j = 0; j < 8; j++) ss += v[j] * v[j];
  #pragma unroll
  for (int o = 32; o; o >>= 1) ss += __shfl_xor(ss, o, 64);
  if ((tid & 63) == 0) red[tid >> 6] = ss;
  __syncthreads();
  float rstd = rsqrtf((red[0] + red[1] + red[2] + red[3]) * (1.0f / 2048.0f) + 1e-5f);
  rstd = bf2f(f2bf(rstd));
  union { uint4 q; u16 s[8]; } ww; ww.q = *(const uint4*)(w + tid * 8);
  union { uint4 q; u16 s[8]; } oo;
  #pragma unroll
  for (int j = 0; j < 8; j++) oo.s[j] = f2bf(scrub(v[j] * rstd * bf2f(ww.s[j]), 200.f));
  *(uint4*)(out + (size_t)row * 2048 + tid * 8) = oo.q;
}

// -------------------------------------------------------------- transpose ---
__global__ __launch_bounds__(256) void transpose_kernel(
    const void* __restrict__ in, u16* __restrict__ out, int R, int C,
    const int* __restrict__ flagp)
{
  __shared__ u16 tile[32][33];
  const int f = *flagp;
  const int tx = threadIdx.x, ty = threadIdx.y;
  const int x = blockIdx.x * 32 + tx;
  const int y0 = blockIdx.y * 32;
  if (f) {
    #pragma unroll
    for (int j = ty; j < 32; j += 8) tile[j][tx] = f2bf(((const float*)in)[(size_t)(y0 + j) * C + x]);
  } else {
    #pragma unroll
    for (int j = ty; j < 32; j += 8) tile[j][tx] = ((const u16*)in)[(size_t)(y0 + j) * C + x];
  }
  __syncthreads();
  const int xo = y0 + tx, yo0 = blockIdx.x * 32;
  #pragma unroll
  for (int j = ty; j < 32; j += 8) out[(size_t)(yo0 + j) * R + xo] = tile[tx][j];
}

// ------------------------------------------------------------------- GEMM ---
// C[M,N] = A[M,K] @ Bt[N,K]^T; m97 structure: global_load_lds width-16
// staging, XOR chunk swizzle p = q ^ ((r>>1)&3).
enum { EPI_STORE = 0, EPI_ADD = 1, EPI_SILU = 2, EPI_ADD_OUT = 3 };

template<int EPI>
__global__ __launch_bounds__(256, 2) void gemm_bt_kernel(
    const u16* __restrict__ A, const u16* __restrict__ Bt,
    void* Cout, const void* aux, int M, int N, int K,
    const int* __restrict__ flagp)
{
  __shared__ alignas(16) u16 As[128 * 32];
  __shared__ alignas(16) u16 Bs[128 * 32];
  const int tid = threadIdx.x;
  const int wid = tid >> 6, lane = tid & 63;
  const int lrow = lane & 15, quad = lane >> 4;
  const int m0 = blockIdx.y * 128, n0 = blockIdx.x * 128;
  const int wm = (wid >> 1) * 64, wn = (wid & 1) * 64;

  const int r0 = tid >> 2, p0 = tid & 3, g0 = p0 ^ ((r0 >> 1) & 3);
  const int r1 = 64 + (tid >> 2), g1 = p0 ^ ((r1 >> 1) & 3);

  const u16* Ar0 = A + (size_t)(m0 + r0) * K + g0 * 8;
  const u16* Ar1 = A + (size_t)(m0 + r1) * K + g1 * 8;
  const u16* Br0 = Bt + (size_t)(n0 + r0) * K + g0 * 8;
  const u16* Br1 = Bt + (size_t)(n0 + r1) * K + g1 * 8;

  f32x4 acc[4][4] = {};

  for (int k0 = 0; k0 < K; k0 += 32) {
    __syncthreads();  // previous tile consumed
    gload16(Ar0 + k0, &As[wid * 512]);
    gload16(Ar1 + k0, &As[2048 + wid * 512]);
    gload16(Br0 + k0, &Bs[wid * 512]);
    gload16(Br1 + k0, &Bs[2048 + wid * 512]);
    __syncthreads();  // vmcnt(0) drained -> LDS valid

    bf16x8 af[4], bfm[4];
    #pragma unroll
    for (int mt = 0; mt < 4; mt++) {
      int r = wm + mt * 16 + lrow;
      int p = quad ^ ((r >> 1) & 3);
      af[mt] = *(const bf16x8*)&As[r * 32 + p * 8];
    }
    #pragma unroll
    for (int nt = 0; nt < 4; nt++) {
      int r = wn + nt * 16 + lrow;
      int p = quad ^ ((r >> 1) & 3);
      bfm[nt] = *(const bf16x8*)&Bs[r * 32 + p * 8];
    }
    #pragma unroll
    for (int mt = 0; mt < 4; mt++)
      #pragma unroll
      for (int nt = 0; nt < 4; nt++)
        acc[mt][nt] = __builtin_amdgcn_mfma_f32_16x16x32_bf16(af[mt], bfm[nt], acc[mt][nt], 0, 0, 0);
  }

  const int oflag = (EPI == EPI_ADD_OUT) ? *flagp : 0;
  #pragma unroll
  for (int mt = 0; mt < 4; mt++)
    #pragma unroll
    for (int nt = 0; nt < 4; nt++)
      #pragma unroll
      for (int i = 0; i < 4; i++) {
        const int row = m0 + wm + mt * 16 + quad * 4 + i;
        const int col = n0 + wn + nt * 16 + lrow;
        const size_t idx = (size_t)row * N + col;
        const float vv = acc[mt][nt][i];
        if (EPI == EPI_STORE) {
          ((u16*)Cout)[idx] = f2bf(scrub(vv, 300.f));
        } else if (EPI == EPI_ADD) {
          ((u16*)Cout)[idx] = f2bf(scrub(bf2f(((const u16*)aux)[idx]) + vv, 700.f));
        } else if (EPI == EPI_SILU) {
          float g = bf2f(((const u16*)aux)[idx]);
          g = fminf(fmaxf(g, -30.f), 30.f);
          const float s = g / (1.0f + __expf(-g));
          ((u16*)Cout)[idx] = f2bf(scrub(s * vv, 800.f));
        } else {
          const float r = scrub(bf2f(((const u16*)aux)[idx]) + vv, 1e6f);
          if (oflag) ((float*)Cout)[idx] = r;
          else       ((u16*)Cout)[idx] = f2bf(r);
        }
      }
}

// ------------------------------------------------------------------- RoPE ---
__global__ __launch_bounds__(256) void rope_kernel(
    u16* qkv, const u16* __restrict__ cosb, const u16* __restrict__ sinb)
{
  const int gw = blockIdx.x * 4 + (threadIdx.x >> 6);
  const int lane = threadIdx.x & 63;
  const int h = gw % 24;
  const int t = gw / 24;
  u16* base = qkv + (size_t)t * 4096 + h * 128;
  const u32 x01 = *(const u32*)(base + 2 * lane);
  const float x1 = bf2f((u16)(x01 & 0xffff));
  const float x2 = bf2f((u16)(x01 >> 16));
  const float c = bf2f(cosb[t * 64 + lane]);
  const float s = bf2f(sinb[t * 64 + lane]);
  const u16 o1 = f2bf(x1 * c - x2 * s);
  const u16 o2 = f2bf(x1 * s + x2 * c);
  base[lane] = o1;
  base[64 + lane] = o2;
}

// ------------------------------------------------------------ flash attn ---
// Kt[64][128] via gload16 (pos p holds chunk p^(r&7)); Vt from global V^T
// with row stride 80 (pos p holds chunk p^(d&7)); Ps chunk-swizzled
// (pos = c ^ (row&7)). Zero-mask fast path via *zerop.
#define VSTR 80
__global__ __launch_bounds__(256, 2) void flash_attn_kernel(
    const u16* __restrict__ qkv, const u16* __restrict__ vT,
    const void* __restrict__ mask, u16* __restrict__ obuf,
    const int* __restrict__ flagp, const int* __restrict__ zerop)
{
  __shared__ alignas(16) u16 Kt[64 * 128];
  __shared__ alignas(16) u16 Vt[128 * VSTR];
  __shared__ alignas(16) u16 Ps[4 * 16 * 64];

  const int qt = blockIdx.x, h = blockIdx.y, b = blockIdx.z;
  const int tid = threadIdx.x;
  const int wid = tid >> 6, lane = tid & 63;
  const int lrow = lane & 15, quad = lane >> 4;
  const int kvh = h >> 1;
  const size_t tok0 = (size_t)b * 2048;
  const int has_mask = *zerop;
  const int mf32 = *flagp;

  bf16x8 qf[4];
  {
    const u16* qptr = qkv + (tok0 + qt * 64 + wid * 16 + lrow) * 4096 + h * 128 + quad * 8;
    #pragma unroll
    for (int kk = 0; kk < 4; kk++) qf[kk] = *(const bf16x8*)(qptr + kk * 32);
  }
  const u16* kbase = qkv + tok0 * 4096 + 2048 + kvh * 128;
  const u16* vbase = vT + (size_t)(kvh * 128) * 4096 + tok0;

  float mst[4] = {-1e30f, -1e30f, -1e30f, -1e30f};
  float lst[4] = {0.f, 0.f, 0.f, 0.f};
  f32x4 oacc[8] = {};
  const float scale = 0.08838834764831845f;  // 1/sqrt(128)

  for (int kt = 0; kt < 32; kt++) {
    __syncthreads();
    // K tile: wave stages 16 rows via 4 gload16 (dest contiguous 1KB each)
    #pragma unroll
    for (int ii = 0; ii < 4; ii++) {
      const int rloc = wid * 16 + ii * 4 + (lane >> 4);
      const int ch = lane & 15;
      const int gch = ch ^ (rloc & 7);
      gload16(kbase + (size_t)(kt * 64 + rloc) * 4096 + gch * 8,
              &Kt[(wid * 16 + ii * 4) * 128]);
    }
    // V tile from global V^T: 1024 chunks, 4/thread, padded-stride LDS rows
    #pragma unroll
    for (int ii = 0; ii < 4; ii++) {
      const int ci = ii * 256 + tid;
      const int d = ci >> 3, c = ci & 7;
      const int pos = c ^ (d & 7);
      const uint4 v = *(const uint4*)(vbase + (size_t)d * 4096 + kt * 64 + c * 8);
      *(uint4*)&Vt[d * VSTR + pos * 8] = v;
    }
    __syncthreads();

    // S = Q @ Ktile^T
    f32x4 sfr[4] = {};
    #pragma unroll
    for (int nt = 0; nt < 4; nt++) {
      const int r = nt * 16 + lrow;
      #pragma unroll
      for (int kk = 0; kk < 4; kk++) {
        bf16x8 kf = *(const bf16x8*)&Kt[r * 128 + (((kk * 4 + quad) ^ (r & 7)) << 3)];
        sfr[nt] = __builtin_amdgcn_mfma_f32_16x16x32_bf16(qf[kk], kf, sfr[nt], 0, 0, 0);
      }
    }
    if (has_mask) {
      #pragma unroll
      for (int nt = 0; nt < 4; nt++)
        #pragma unroll
        for (int i = 0; i < 4; i++) {
          const size_t midx = (tok0 + qt * 64 + wid * 16 + quad * 4 + i) * 2048
                              + kt * 64 + nt * 16 + lrow;
          const float mv = mf32 ? ((const float*)mask)[midx] : bf2f(((const u16*)mask)[midx]);
          sfr[nt][i] = fminf(fmaxf(sfr[nt][i] * scale + mv, -1e4f), 1e4f);
        }
    } else {
      #pragma unroll
      for (int nt = 0; nt < 4; nt++)
        #pragma unroll
        for (int i = 0; i < 4; i++)
          sfr[nt][i] = fminf(fmaxf(sfr[nt][i] * scale, -1e4f), 1e4f);
    }
    // online softmax; row quad*4+i lives in this quad's 16 lanes
    float alpha[4], mnew[4], rsum[4];
    #pragma unroll
    for (int i = 0; i < 4; i++) {
      float mx = fmaxf(fmaxf(sfr[0][i], sfr[1][i]), fmaxf(sfr[2][i], sfr[3][i]));
      #pragma unroll
      for (int o = 8; o; o >>= 1) mx = fmaxf(mx, __shfl_xor(mx, o, 64));
      mnew[i] = fmaxf(mst[i], mx);
      alpha[i] = __expf(mst[i] - mnew[i]);
      mst[i] = mnew[i];
      rsum[i] = 0.f;
    }
    #pragma unroll
    for (int nt = 0; nt < 4; nt++)
      #pragma unroll
      for (int i = 0; i < 4; i++) {
        const float p = __expf(sfr[nt][i] - mnew[i]);
        rsum[i] += p;
        const int row = quad * 4 + i;
        const int c = nt * 2 + (lrow >> 3);          // col chunk
        Ps[wid * 1024 + row * 64 + ((c ^ (row & 7)) << 3) + (lrow & 7)] = f2bf(p);
      }
    #pragma unroll
    for (int i = 0; i < 4; i++) {
      #pragma unroll
      for (int o = 8; o; o >>= 1) rsum[i] += __shfl_xor(rsum[i], o, 64);
      lst[i] = lst[i] * alpha[i] + rsum[i];
    }
    #pragma unroll
    for (int dt = 0; dt < 8; dt++)
      #pragma unroll
      for (int i = 0; i < 4; i++) oacc[dt][i] *= alpha[i];

    asm volatile("s_waitcnt lgkmcnt(0)" ::: "memory");  // own-wave P writes landed
    // O += P @ V
    #pragma unroll
    for (int kk = 0; kk < 2; kk++) {
      bf16x8 pf = *(const bf16x8*)&Ps[wid * 1024 + lrow * 64 + (((kk * 4 + quad) ^ (lrow & 7)) << 3)];
      #pragma unroll
      for (int dt = 0; dt < 8; dt++) {
        const int d = dt * 16 + lrow;
        bf16x8 vf = *(const bf16x8*)&Vt[d * VSTR + (((kk * 4 + quad) ^ (d & 7)) << 3)];
        oacc[dt] = __builtin_amdgcn_mfma_f32_16x16x32_bf16(pf, vf, oacc[dt], 0, 0, 0);
      }
    }
  }

  #pragma unroll
  for (int dt = 0; dt < 8; dt++)
    #pragma unroll
    for (int i = 0; i < 4; i++) {
      const size_t tok = tok0 + qt * 64 + wid * 16 + quad * 4 + i;
      obuf[tok * 2048 + h * 128 + dt * 16 + lrow] = f2bf(scrub(oacc[dt][i] / lst[i], 500.f));
    }
}

// ----------------------------------------------------------------- launch ---
extern "C" void kernel_launch(void* const* d_in, const int* in_sizes, int n_in,
                              void* d_out, int out_size, void* d_ws, size_t ws_size,
                              hipStream_t stream) {
  (void)in_sizes; (void)n_in; (void)out_size; (void)ws_size;
  const void* hs   = d_in[0];
  const void* cosi = d_in[1];
  const void* sini = d_in[2];
  const void* mask = d_in[3];
  const void* wq   = d_in[4];
  const void* wk   = d_in[5];
  const void* wv   = d_in[6];
  const void* wo   = d_in[7];
  const void* wg   = d_in[8];
  const void* wu   = d_in[9];
  const void* wd   = d_in[10];
  const void* ln1  = d_in[11];
  const void* ln2  = d_in[12];

  char* ws = (char*)d_ws;                          // 178 MB total
  int* flag  = (int*)ws;                           // dtype flag
  int* flag2 = (int*)(ws + 64);                    // mask-nonzero flag
  u16* ln1b  = (u16*)(ws + 4096);
  u16* ln2b  = (u16*)(ws + 16384);
  u16* cosb  = (u16*)(ws + (1u << 20));
  u16* sinb  = (u16*)(ws + (1u << 20) + (1u << 19));
  u16* hsb   = (u16*)(ws + (2u  << 20));           // 16 MB bf16 hidden_states
  u16* xn    = (u16*)(ws + (18u << 20));           // 16 MB normed x; later h2
  u16* qkv   = (u16*)(ws + (34u << 20));           // 32 MB fused q|k (V unused)
  u16* abuf  = (u16*)(ws + (66u << 20));           // 16 MB attention out
  u16* wT    = (u16*)(ws + (82u << 20));           // 32 MB transposed weights
  u16* gbuf  = (u16*)(ws + (114u << 20));          // 64 MB gate/h (MLP phase)
  u16* vT    = gbuf;                               //  8 MB V^T (dead pre-MLP)
  u16* x2n   = hsb;                                // hsb dead after O-proj
  u16* h2    = xn;                                 // xn dead after QKV gemm

  dim3 tb(32, 8);
  detect_kernel<<<1, 256, 0, stream>>>((const u16*)hs, flag);
  init_flag2_kernel<<<1, 1, 0, stream>>>(flag2);
  detect_mask_kernel<<<2048, 256, 0, stream>>>(mask, 8388608, flag, flag2);
  // bf16 input arena
  convert_kernel<<<8192, 256, 0, stream>>>(hs,   hsb,  8388608, flag);
  convert_kernel<<<256,  256, 0, stream>>>(cosi, cosb, 262144,  flag);
  convert_kernel<<<256,  256, 0, stream>>>(sini, sinb, 262144,  flag);
  convert_kernel<<<2,    256, 0, stream>>>(ln1,  ln1b, 2048,    flag);
  convert_kernel<<<2,    256, 0, stream>>>(ln2,  ln2b, 2048,    flag);
  // LN1
  rmsnorm_kernel<<<4096, 256, 0, stream>>>(hsb, ln1b, xn);
  // weights: wq^T | wk^T | wv^T stacked as [4096][2048]
  transpose_kernel<<<dim3(64, 64), tb, 0, stream>>>(wq, wT, 2048, 2048, flag);
  transpose_kernel<<<dim3(32, 64), tb, 0, stream>>>(wk, wT + (size_t)2048 * 2048, 2048, 1024, flag);
  transpose_kernel<<<dim3(32, 64), tb, 0, stream>>>(wv, wT + (size_t)3072 * 2048, 2048, 1024, flag);
  // Q|K projection (N=3072) and V^T = wv^T @ xn^T (M=1024, N=4096)
  gemm_bt_kernel<EPI_STORE><<<dim3(24, 32), 256, 0, stream>>>(xn, wT, qkv, nullptr, 4096, 4096, 2048, flag);
  gemm_bt_kernel<EPI_STORE><<<dim3(32, 8), 256, 0, stream>>>(wT + (size_t)3072 * 2048, xn, vT, nullptr, 1024, 4096, 2048, flag);
  // RoPE on q and k heads
  rope_kernel<<<24576, 256, 0, stream>>>(qkv, cosb, sinb);
  // attention
  flash_attn_kernel<<<dim3(32, 16, 2), 256, 0, stream>>>(qkv, vT, mask, abuf, flag, flag2);
  // O proj + residual -> h2
  transpose_kernel<<<dim3(64, 64), tb, 0, stream>>>(wo, wT, 2048, 2048, flag);
  gemm_bt_kernel<EPI_ADD><<<dim3(16, 32), 256, 0, stream>>>(abuf, wT, h2, hsb, 4096, 2048, 2048, flag);
  // LN2
  rmsnorm_kernel<<<4096, 256, 0, stream>>>(h2, ln2b, x2n);
  // MLP
  transpose_kernel<<<dim3(256, 64), tb, 0, stream>>>(wg, wT, 2048, 8192, flag);
  gemm_bt_kernel<EPI_STORE><<<dim3(64, 32), 256, 0, stream>>>(x2n, wT, gbuf, nullptr, 4096, 8192, 2048, flag);
  transpose_kernel<<<dim3(256, 64), tb, 0, stream>>>(wu, wT, 2048, 8192, flag);
  gemm_bt_kernel<EPI_SILU><<<dim3(64, 32), 256, 0, stream>>>(x2n, wT, gbuf, gbuf, 4096, 8192, 2048, flag);
  transpose_kernel<<<dim3(64, 256), tb, 0, stream>>>(wd, wT, 8192, 2048, flag);
  gemm_bt_kernel<EPI_ADD_OUT><<<dim3(16, 32), 256, 0, stream>>>(gbuf, wT, d_out, h2, 4096, 2048, 8192, flag);
}

// Round 5
// 1224.145 us; speedup vs baseline: 1.1797x; 1.0128x over previous
//
#include <hip/hip_runtime.h>
#include <stdint.h>

typedef unsigned short u16;
typedef unsigned int u32;
typedef short bf16x8 __attribute__((ext_vector_type(8)));
typedef float f32x4 __attribute__((ext_vector_type(4)));

#define AS_GLOBAL __attribute__((address_space(1)))
#define AS_LDS    __attribute__((address_space(3)))

__device__ __forceinline__ float bf2f(u16 h) {
  union { u32 u; float f; } v; v.u = ((u32)h) << 16; return v.f;
}
__device__ __forceinline__ u16 f2bf(float f) {
  union { float f; u32 u; } v; v.f = f;
  return (u16)((v.u + 0x7FFFu + ((v.u >> 16) & 1u)) >> 16);
}
__device__ __forceinline__ float scrub(float v, float mark) {
  return (v == v && fabsf(v) < 1e30f) ? v : mark;
}
// async global->LDS, 16B/lane; LDS dest = wave-uniform base + lane*16.
__device__ __forceinline__ void gload16(const void* g, void* l) {
  __builtin_amdgcn_global_load_lds((const AS_GLOBAL u32*)g, (AS_LDS u32*)l, 16, 0, 0);
}

// -------------------------------------------------------------- detectors ---
// dtype: sample even-index u16s of hidden_states; bf16 -> sane exponents.
__global__ __launch_bounds__(256) void detect_kernel(const u16* __restrict__ hs, int* flagp) {
  __shared__ int cnt;
  if (threadIdx.x == 0) cnt = 0;
  __syncthreads();
  int sane = 0;
  #pragma unroll
  for (int j = 0; j < 4; j++) {
    const u16 v = hs[(threadIdx.x * 4 + j) * 2];
    const int e = (v >> 7) & 0xFF;
    sane += (e >= 0x60 && e <= 0x8E) ? 1 : 0;
  }
  atomicAdd(&cnt, sane);
  __syncthreads();
  if (threadIdx.x == 0) *flagp = (cnt < 600) ? 1 : 0;
}

__global__ void init_flag2_kernel(int* flag2p) { *flag2p = 0; }

// set flag2=1 if any nonzero bits in mask (size n elems; width per *flagp).
__global__ __launch_bounds__(256) void detect_mask_kernel(
    const void* __restrict__ mask, int n, const int* __restrict__ flagp, int* flag2p) {
  const int f = *flagp;
  const size_t nq = (size_t)n * (f ? 4 : 2) / 16;  // # uint4
  u32 acc = 0;
  for (size_t i = blockIdx.x * 256 + threadIdx.x; i < nq; i += (size_t)gridDim.x * 256) {
    const uint4 v = ((const uint4*)mask)[i];
    acc |= v.x | v.y | v.z | v.w;
  }
  if (__ballot(acc != 0) != 0ull && (threadIdx.x & 63) == 0)
    atomicOr(flag2p, 1);
}

// ------------------------------------------------------------- converter ---
__global__ __launch_bounds__(256) void convert_kernel(
    const void* __restrict__ src, u16* __restrict__ dst, int n, const int* __restrict__ flagp) {
  const int f = *flagp;
  const int i = (blockIdx.x * 256 + threadIdx.x) * 4;
  if (i >= n) return;
  union { uint2 u; u16 s[4]; } o;
  if (f) {
    const float4 v = *(const float4*)((const float*)src + i);
    o.s[0] = f2bf(v.x); o.s[1] = f2bf(v.y); o.s[2] = f2bf(v.z); o.s[3] = f2bf(v.w);
  } else {
    o.u = *(const uint2*)((const u16*)src + i);
  }
  *(uint2*)(dst + i) = o.u;
}

// --------------------------------------------------- RMSNorm (fused LN1) ---
// reads raw input (fp32 if *flagp else bf16), writes bf16 copy + normed row.
__global__ __launch_bounds__(256) void rmsnorm_in_kernel(
    const void* __restrict__ xin, const u16* __restrict__ w,
    u16* __restrict__ out, u16* __restrict__ srccopy, const int* __restrict__ flagp)
{
  __shared__ float red[4];
  const int row = blockIdx.x, tid = threadIdx.x;
  const int f = *flagp;
  union { uint4 q; u16 s[8]; } uu;
  if (f) {
    const float* xr = (const float*)xin + (size_t)row * 2048 + tid * 8;
    const float4 a = *(const float4*)xr, b = *(const float4*)(xr + 4);
    const float t[8] = {a.x, a.y, a.z, a.w, b.x, b.y, b.z, b.w};
    #pragma unroll
    for (int j = 0; j < 8; j++) uu.s[j] = f2bf(t[j]);
  } else {
    uu.q = *(const uint4*)((const u16*)xin + (size_t)row * 2048 + tid * 8);
  }
  *(uint4*)(srccopy + (size_t)row * 2048 + tid * 8) = uu.q;
  float v[8];
  #pragma unroll
  for (int j = 0; j < 8; j++) v[j] = bf2f(uu.s[j]);
  float ss = 0.f;
  #pragma unroll
  for (int j = 0; j < 8; j++) ss += v[j] * v[j];
  #pragma unroll
  for (int o = 32; o; o >>= 1) ss += __shfl_xor(ss, o, 64);
  if ((tid & 63) == 0) red[tid >> 6] = ss;
  __syncthreads();
  float rstd = rsqrtf((red[0] + red[1] + red[2] + red[3]) * (1.0f / 2048.0f) + 1e-5f);
  rstd = bf2f(f2bf(rstd));
  union { uint4 q; u16 s[8]; } ww; ww.q = *(const uint4*)(w + tid * 8);
  union { uint4 q; u16 s[8]; } oo;
  #pragma unroll
  for (int j = 0; j < 8; j++) oo.s[j] = f2bf(scrub(v[j] * rstd * bf2f(ww.s[j]), 200.f));
  *(uint4*)(out + (size_t)row * 2048 + tid * 8) = oo.q;
}

// ---------------------------------------------------------------- RMSNorm ---
__global__ __launch_bounds__(256) void rmsnorm_kernel(
    const u16* __restrict__ xin, const u16* __restrict__ w, u16* __restrict__ out)
{
  __shared__ float red[4];
  const int row = blockIdx.x, tid = threadIdx.x;
  const u16* xr = xin + (size_t)row * 2048 + tid * 8;
  union { uint4 q; u16 s[8]; } uu; uu.q = *(const uint4*)xr;
  float v[8];
  #pragma unroll
  for (int j = 0; j < 8; j++) v[j] = bf2f(uu.s[j]);
  float ss = 0.f;
  #pragma unroll
  for (int j = 0; j < 8; j++) ss += v[j] * v[j];
  #pragma unroll
  for (int o = 32; o; o >>= 1) ss += __shfl_xor(ss, o, 64);
  if ((tid & 63) == 0) red[tid >> 6] = ss;
  __syncthreads();
  float rstd = rsqrtf((red[0] + red[1] + red[2] + red[3]) * (1.0f / 2048.0f) + 1e-5f);
  rstd = bf2f(f2bf(rstd));
  union { uint4 q; u16 s[8]; } ww; ww.q = *(const uint4*)(w + tid * 8);
  union { uint4 q; u16 s[8]; } oo;
  #pragma unroll
  for (int j = 0; j < 8; j++) oo.s[j] = f2bf(scrub(v[j] * rstd * bf2f(ww.s[j]), 200.f));
  *(uint4*)(out + (size_t)row * 2048 + tid * 8) = oo.q;
}

// -------------------------------------------------------------- transpose ---
__global__ __launch_bounds__(256) void transpose_kernel(
    const void* __restrict__ in, u16* __restrict__ out, int R, int C,
    const int* __restrict__ flagp)
{
  __shared__ u16 tile[32][33];
  const int f = *flagp;
  const int tx = threadIdx.x, ty = threadIdx.y;
  const int x = blockIdx.x * 32 + tx;
  const int y0 = blockIdx.y * 32;
  if (f) {
    #pragma unroll
    for (int j = ty; j < 32; j += 8) tile[j][tx] = f2bf(((const float*)in)[(size_t)(y0 + j) * C + x]);
  } else {
    #pragma unroll
    for (int j = ty; j < 32; j += 8) tile[j][tx] = ((const u16*)in)[(size_t)(y0 + j) * C + x];
  }
  __syncthreads();
  const int xo = y0 + tx, yo0 = blockIdx.x * 32;
  #pragma unroll
  for (int j = ty; j < 32; j += 8) out[(size_t)(yo0 + j) * R + xo] = tile[tx][j];
}

// ------------------------------------------------------------------- GEMM ---
// C[M,N] = A[M,K] @ Bt[N,K]^T; m97 structure (gload16 width-16 staging, XOR
// chunk swizzle). 1D grid with L2-locality remap: column-bands of 16 M-rows
// so the resident block cohort's strip working set fits aggregate L2.
enum { EPI_STORE = 0, EPI_ADD = 1, EPI_SILU = 2, EPI_ADD_OUT = 3 };

template<int EPI>
__global__ __launch_bounds__(256, 2) void gemm_bt_kernel(
    const u16* __restrict__ A, const u16* __restrict__ Bt,
    void* Cout, const void* aux, int M, int N, int K,
    int gx, int gy, const int* __restrict__ flagp)
{
  __shared__ alignas(16) u16 As[128 * 32];
  __shared__ alignas(16) u16 Bs[128 * 32];
  const int tid = threadIdx.x;
  const int wid = tid >> 6, lane = tid & 63;
  const int lrow = lane & 15, quad = lane >> 4;

  // L2-locality swizzle (bijection): 16-row bands, columns advance slowest.
  const int bandh = ((gy & 15) == 0) ? 16 : gy;
  const int per = gx * bandh;
  const int band = blockIdx.x / per;
  const int wrem = blockIdx.x - band * per;
  const int by = band * bandh + (wrem % bandh);
  const int bx = wrem / bandh;
  const int m0 = by * 128, n0 = bx * 128;

  const int wm = (wid >> 1) * 64, wn = (wid & 1) * 64;

  const int r0 = tid >> 2, p0 = tid & 3, g0 = p0 ^ ((r0 >> 1) & 3);
  const int r1 = 64 + (tid >> 2), g1 = p0 ^ ((r1 >> 1) & 3);

  const u16* Ar0 = A + (size_t)(m0 + r0) * K + g0 * 8;
  const u16* Ar1 = A + (size_t)(m0 + r1) * K + g1 * 8;
  const u16* Br0 = Bt + (size_t)(n0 + r0) * K + g0 * 8;
  const u16* Br1 = Bt + (size_t)(n0 + r1) * K + g1 * 8;

  f32x4 acc[4][4] = {};

  for (int k0 = 0; k0 < K; k0 += 32) {
    __syncthreads();  // previous tile consumed
    gload16(Ar0 + k0, &As[wid * 512]);
    gload16(Ar1 + k0, &As[2048 + wid * 512]);
    gload16(Br0 + k0, &Bs[wid * 512]);
    gload16(Br1 + k0, &Bs[2048 + wid * 512]);
    __syncthreads();  // vmcnt(0) drained -> LDS valid

    bf16x8 af[4], bfm[4];
    #pragma unroll
    for (int mt = 0; mt < 4; mt++) {
      int r = wm + mt * 16 + lrow;
      int p = quad ^ ((r >> 1) & 3);
      af[mt] = *(const bf16x8*)&As[r * 32 + p * 8];
    }
    #pragma unroll
    for (int nt = 0; nt < 4; nt++) {
      int r = wn + nt * 16 + lrow;
      int p = quad ^ ((r >> 1) & 3);
      bfm[nt] = *(const bf16x8*)&Bs[r * 32 + p * 8];
    }
    #pragma unroll
    for (int mt = 0; mt < 4; mt++)
      #pragma unroll
      for (int nt = 0; nt < 4; nt++)
        acc[mt][nt] = __builtin_amdgcn_mfma_f32_16x16x32_bf16(af[mt], bfm[nt], acc[mt][nt], 0, 0, 0);
  }

  const int oflag = (EPI == EPI_ADD_OUT) ? *flagp : 0;
  #pragma unroll
  for (int mt = 0; mt < 4; mt++)
    #pragma unroll
    for (int nt = 0; nt < 4; nt++)
      #pragma unroll
      for (int i = 0; i < 4; i++) {
        const int row = m0 + wm + mt * 16 + quad * 4 + i;
        const int col = n0 + wn + nt * 16 + lrow;
        const size_t idx = (size_t)row * N + col;
        const float vv = acc[mt][nt][i];
        if (EPI == EPI_STORE) {
          ((u16*)Cout)[idx] = f2bf(scrub(vv, 300.f));
        } else if (EPI == EPI_ADD) {
          ((u16*)Cout)[idx] = f2bf(scrub(bf2f(((const u16*)aux)[idx]) + vv, 700.f));
        } else if (EPI == EPI_SILU) {
          float g = bf2f(((const u16*)aux)[idx]);
          g = fminf(fmaxf(g, -30.f), 30.f);
          const float s = g / (1.0f + __expf(-g));
          ((u16*)Cout)[idx] = f2bf(scrub(s * vv, 800.f));
        } else {
          const float r = scrub(bf2f(((const u16*)aux)[idx]) + vv, 1e6f);
          if (oflag) ((float*)Cout)[idx] = r;
          else       ((u16*)Cout)[idx] = f2bf(r);
        }
      }
}

// ------------------------------------------------------------------- RoPE ---
__global__ __launch_bounds__(256) void rope_kernel(
    u16* qkv, const u16* __restrict__ cosb, const u16* __restrict__ sinb)
{
  const int gw = blockIdx.x * 4 + (threadIdx.x >> 6);
  const int lane = threadIdx.x & 63;
  const int h = gw % 24;
  const int t = gw / 24;
  u16* base = qkv + (size_t)t * 4096 + h * 128;
  const u32 x01 = *(const u32*)(base + 2 * lane);
  const float x1 = bf2f((u16)(x01 & 0xffff));
  const float x2 = bf2f((u16)(x01 >> 16));
  const float c = bf2f(cosb[t * 64 + lane]);
  const float s = bf2f(sinb[t * 64 + lane]);
  const u16 o1 = f2bf(x1 * c - x2 * s);
  const u16 o2 = f2bf(x1 * s + x2 * c);
  base[lane] = o1;
  base[64 + lane] = o2;
}

// ------------------------------------------------------------ flash attn ---
#define VSTR 80
__global__ __launch_bounds__(256, 2) void flash_attn_kernel(
    const u16* __restrict__ qkv, const u16* __restrict__ vT,
    const void* __restrict__ mask, u16* __restrict__ obuf,
    const int* __restrict__ flagp, const int* __restrict__ zerop)
{
  __shared__ alignas(16) u16 Kt[64 * 128];
  __shared__ alignas(16) u16 Vt[128 * VSTR];
  __shared__ alignas(16) u16 Ps[4 * 16 * 64];

  const int qt = blockIdx.x, h = blockIdx.y, b = blockIdx.z;
  const int tid = threadIdx.x;
  const int wid = tid >> 6, lane = tid & 63;
  const int lrow = lane & 15, quad = lane >> 4;
  const int kvh = h >> 1;
  const size_t tok0 = (size_t)b * 2048;
  const int has_mask = *zerop;
  const int mf32 = *flagp;

  bf16x8 qf[4];
  {
    const u16* qptr = qkv + (tok0 + qt * 64 + wid * 16 + lrow) * 4096 + h * 128 + quad * 8;
    #pragma unroll
    for (int kk = 0; kk < 4; kk++) qf[kk] = *(const bf16x8*)(qptr + kk * 32);
  }
  const u16* kbase = qkv + tok0 * 4096 + 2048 + kvh * 128;
  const u16* vbase = vT + (size_t)(kvh * 128) * 4096 + tok0;

  float mst[4] = {-1e30f, -1e30f, -1e30f, -1e30f};
  float lst[4] = {0.f, 0.f, 0.f, 0.f};
  f32x4 oacc[8] = {};
  const float scale = 0.08838834764831845f;  // 1/sqrt(128)

  for (int kt = 0; kt < 32; kt++) {
    __syncthreads();
    #pragma unroll
    for (int ii = 0; ii < 4; ii++) {
      const int rloc = wid * 16 + ii * 4 + (lane >> 4);
      const int ch = lane & 15;
      const int gch = ch ^ (rloc & 7);
      gload16(kbase + (size_t)(kt * 64 + rloc) * 4096 + gch * 8,
              &Kt[(wid * 16 + ii * 4) * 128]);
    }
    #pragma unroll
    for (int ii = 0; ii < 4; ii++) {
      const int ci = ii * 256 + tid;
      const int d = ci >> 3, c = ci & 7;
      const int pos = c ^ (d & 7);
      const uint4 v = *(const uint4*)(vbase + (size_t)d * 4096 + kt * 64 + c * 8);
      *(uint4*)&Vt[d * VSTR + pos * 8] = v;
    }
    __syncthreads();

    f32x4 sfr[4] = {};
    #pragma unroll
    for (int nt = 0; nt < 4; nt++) {
      const int r = nt * 16 + lrow;
      #pragma unroll
      for (int kk = 0; kk < 4; kk++) {
        bf16x8 kf = *(const bf16x8*)&Kt[r * 128 + (((kk * 4 + quad) ^ (r & 7)) << 3)];
        sfr[nt] = __builtin_amdgcn_mfma_f32_16x16x32_bf16(qf[kk], kf, sfr[nt], 0, 0, 0);
      }
    }
    if (has_mask) {
      #pragma unroll
      for (int nt = 0; nt < 4; nt++)
        #pragma unroll
        for (int i = 0; i < 4; i++) {
          const size_t midx = (tok0 + qt * 64 + wid * 16 + quad * 4 + i) * 2048
                              + kt * 64 + nt * 16 + lrow;
          const float mv = mf32 ? ((const float*)mask)[midx] : bf2f(((const u16*)mask)[midx]);
          sfr[nt][i] = fminf(fmaxf(sfr[nt][i] * scale + mv, -1e4f), 1e4f);
        }
    } else {
      #pragma unroll
      for (int nt = 0; nt < 4; nt++)
        #pragma unroll
        for (int i = 0; i < 4; i++)
          sfr[nt][i] = fminf(fmaxf(sfr[nt][i] * scale, -1e4f), 1e4f);
    }
    float alpha[4], mnew[4], rsum[4];
    #pragma unroll
    for (int i = 0; i < 4; i++) {
      float mx = fmaxf(fmaxf(sfr[0][i], sfr[1][i]), fmaxf(sfr[2][i], sfr[3][i]));
      #pragma unroll
      for (int o = 8; o; o >>= 1) mx = fmaxf(mx, __shfl_xor(mx, o, 64));
      mnew[i] = fmaxf(mst[i], mx);
      alpha[i] = __expf(mst[i] - mnew[i]);
      mst[i] = mnew[i];
      rsum[i] = 0.f;
    }
    #pragma unroll
    for (int nt = 0; nt < 4; nt++)
      #pragma unroll
      for (int i = 0; i < 4; i++) {
        const float p = __expf(sfr[nt][i] - mnew[i]);
        rsum[i] += p;
        const int row = quad * 4 + i;
        const int c = nt * 2 + (lrow >> 3);
        Ps[wid * 1024 + row * 64 + ((c ^ (row & 7)) << 3) + (lrow & 7)] = f2bf(p);
      }
    #pragma unroll
    for (int i = 0; i < 4; i++) {
      #pragma unroll
      for (int o = 8; o; o >>= 1) rsum[i] += __shfl_xor(rsum[i], o, 64);
      lst[i] = lst[i] * alpha[i] + rsum[i];
    }
    #pragma unroll
    for (int dt = 0; dt < 8; dt++)
      #pragma unroll
      for (int i = 0; i < 4; i++) oacc[dt][i] *= alpha[i];

    asm volatile("s_waitcnt lgkmcnt(0)" ::: "memory");
    #pragma unroll
    for (int kk = 0; kk < 2; kk++) {
      bf16x8 pf = *(const bf16x8*)&Ps[wid * 1024 + lrow * 64 + (((kk * 4 + quad) ^ (lrow & 7)) << 3)];
      #pragma unroll
      for (int dt = 0; dt < 8; dt++) {
        const int d = dt * 16 + lrow;
        bf16x8 vf = *(const bf16x8*)&Vt[d * VSTR + (((kk * 4 + quad) ^ (d & 7)) << 3)];
        oacc[dt] = __builtin_amdgcn_mfma_f32_16x16x32_bf16(pf, vf, oacc[dt], 0, 0, 0);
      }
    }
  }

  #pragma unroll
  for (int dt = 0; dt < 8; dt++)
    #pragma unroll
    for (int i = 0; i < 4; i++) {
      const size_t tok = tok0 + qt * 64 + wid * 16 + quad * 4 + i;
      obuf[tok * 2048 + h * 128 + dt * 16 + lrow] = f2bf(scrub(oacc[dt][i] / lst[i], 500.f));
    }
}

// ----------------------------------------------------------------- launch ---
extern "C" void kernel_launch(void* const* d_in, const int* in_sizes, int n_in,
                              void* d_out, int out_size, void* d_ws, size_t ws_size,
                              hipStream_t stream) {
  (void)in_sizes; (void)n_in; (void)out_size; (void)ws_size;
  const void* hs   = d_in[0];
  const void* cosi = d_in[1];
  const void* sini = d_in[2];
  const void* mask = d_in[3];
  const void* wq   = d_in[4];
  const void* wk   = d_in[5];
  const void* wv   = d_in[6];
  const void* wo   = d_in[7];
  const void* wg   = d_in[8];
  const void* wu   = d_in[9];
  const void* wd   = d_in[10];
  const void* ln1  = d_in[11];
  const void* ln2  = d_in[12];

  char* ws = (char*)d_ws;                          // 178 MB total
  int* flag  = (int*)ws;                           // dtype flag
  int* flag2 = (int*)(ws + 64);                    // mask-nonzero flag
  u16* ln1b  = (u16*)(ws + 4096);
  u16* ln2b  = (u16*)(ws + 16384);
  u16* cosb  = (u16*)(ws + (1u << 20));
  u16* sinb  = (u16*)(ws + (1u << 20) + (1u << 19));
  u16* hsb   = (u16*)(ws + (2u  << 20));           // 16 MB bf16 hidden_states
  u16* xn    = (u16*)(ws + (18u << 20));           // 16 MB normed x; later h2
  u16* qkv   = (u16*)(ws + (34u << 20));           // 32 MB fused q|k (V unused)
  u16* abuf  = (u16*)(ws + (66u << 20));           // 16 MB attention out
  u16* wT    = (u16*)(ws + (82u << 20));           // 32 MB transposed weights
  u16* gbuf  = (u16*)(ws + (114u << 20));          // 64 MB gate/h (MLP phase)
  u16* vT    = gbuf;                               //  8 MB V^T (dead pre-MLP)
  u16* x2n   = hsb;                                // hsb dead after O-proj
  u16* h2    = xn;                                 // xn dead after QKV gemm

  dim3 tb(32, 8);
  detect_kernel<<<1, 256, 0, stream>>>((const u16*)hs, flag);
  init_flag2_kernel<<<1, 1, 0, stream>>>(flag2);
  detect_mask_kernel<<<2048, 256, 0, stream>>>(mask, 8388608, flag, flag2);
  // small converts
  convert_kernel<<<256,  256, 0, stream>>>(cosi, cosb, 262144,  flag);
  convert_kernel<<<256,  256, 0, stream>>>(sini, sinb, 262144,  flag);
  convert_kernel<<<2,    256, 0, stream>>>(ln1,  ln1b, 2048,    flag);
  convert_kernel<<<2,    256, 0, stream>>>(ln2,  ln2b, 2048,    flag);
  // LN1 fused with input conversion (writes hsb copy + xn)
  rmsnorm_in_kernel<<<4096, 256, 0, stream>>>(hs, ln1b, xn, hsb, flag);
  // weights: wq^T | wk^T | wv^T stacked as [4096][2048]
  transpose_kernel<<<dim3(64, 64), tb, 0, stream>>>(wq, wT, 2048, 2048, flag);
  transpose_kernel<<<dim3(32, 64), tb, 0, stream>>>(wk, wT + (size_t)2048 * 2048, 2048, 1024, flag);
  transpose_kernel<<<dim3(32, 64), tb, 0, stream>>>(wv, wT + (size_t)3072 * 2048, 2048, 1024, flag);
  // Q|K projection (cols 0..3071 of stride-4096 qkv) and V^T = wv^T @ xn^T
  gemm_bt_kernel<EPI_STORE><<<24 * 32, 256, 0, stream>>>(xn, wT, qkv, nullptr, 4096, 4096, 2048, 24, 32, flag);
  gemm_bt_kernel<EPI_STORE><<<32 * 8, 256, 0, stream>>>(wT + (size_t)3072 * 2048, xn, vT, nullptr, 1024, 4096, 2048, 32, 8, flag);
  // RoPE on q and k heads
  rope_kernel<<<24576, 256, 0, stream>>>(qkv, cosb, sinb);
  // attention
  flash_attn_kernel<<<dim3(32, 16, 2), 256, 0, stream>>>(qkv, vT, mask, abuf, flag, flag2);
  // O proj + residual -> h2
  transpose_kernel<<<dim3(64, 64), tb, 0, stream>>>(wo, wT, 2048, 2048, flag);
  gemm_bt_kernel<EPI_ADD><<<16 * 32, 256, 0, stream>>>(abuf, wT, h2, hsb, 4096, 2048, 2048, 16, 32, flag);
  // LN2
  rmsnorm_kernel<<<4096, 256, 0, stream>>>(h2, ln2b, x2n);
  // MLP
  transpose_kernel<<<dim3(256, 64), tb, 0, stream>>>(wg, wT, 2048, 8192, flag);
  gemm_bt_kernel<EPI_STORE><<<64 * 32, 256, 0, stream>>>(x2n, wT, gbuf, nullptr, 4096, 8192, 2048, 64, 32, flag);
  transpose_kernel<<<dim3(256, 64), tb, 0, stream>>>(wu, wT, 2048, 8192, flag);
  gemm_bt_kernel<EPI_SILU><<<64 * 32, 256, 0, stream>>>(x2n, wT, gbuf, gbuf, 4096, 8192, 2048, 64, 32, flag);
  transpose_kernel<<<dim3(64, 256), tb, 0, stream>>>(wd, wT, 8192, 2048, flag);
  gemm_bt_kernel<EPI_ADD_OUT><<<16 * 32, 256, 0, stream>>>(gbuf, wT, d_out, h2, 4096, 2048, 8192, 16, 32, flag);
}

// Round 6
// 1143.643 us; speedup vs baseline: 1.2627x; 1.0704x over previous
//
#include <hip/hip_runtime.h>
#include <stdint.h>

typedef unsigned short u16;
typedef unsigned int u32;
typedef short bf16x8 __attribute__((ext_vector_type(8)));
typedef float f32x4 __attribute__((ext_vector_type(4)));

#define AS_GLOBAL __attribute__((address_space(1)))
#define AS_LDS    __attribute__((address_space(3)))

__device__ __forceinline__ float bf2f(u16 h) {
  union { u32 u; float f; } v; v.u = ((u32)h) << 16; return v.f;
}
__device__ __forceinline__ u16 f2bf(float f) {
  union { float f; u32 u; } v; v.f = f;
  return (u16)((v.u + 0x7FFFu + ((v.u >> 16) & 1u)) >> 16);
}
__device__ __forceinline__ float scrub(float v, float mark) {
  return (v == v && fabsf(v) < 1e30f) ? v : mark;
}
// async global->LDS, 16B/lane; LDS dest = wave-uniform base + lane*16.
__device__ __forceinline__ void gload16(const void* g, void* l) {
  __builtin_amdgcn_global_load_lds((const AS_GLOBAL u32*)g, (AS_LDS u32*)l, 16, 0, 0);
}

// -------------------------------------------------------------- detectors ---
__global__ __launch_bounds__(256) void detect_kernel(const u16* __restrict__ hs, int* flagp) {
  __shared__ int cnt;
  if (threadIdx.x == 0) cnt = 0;
  __syncthreads();
  int sane = 0;
  #pragma unroll
  for (int j = 0; j < 4; j++) {
    const u16 v = hs[(threadIdx.x * 4 + j) * 2];
    const int e = (v >> 7) & 0xFF;
    sane += (e >= 0x60 && e <= 0x8E) ? 1 : 0;
  }
  atomicAdd(&cnt, sane);
  __syncthreads();
  if (threadIdx.x == 0) *flagp = (cnt < 600) ? 1 : 0;
}

__global__ void init_flag2_kernel(int* flag2p) { *flag2p = 0; }

__global__ __launch_bounds__(256) void detect_mask_kernel(
    const void* __restrict__ mask, int n, const int* __restrict__ flagp, int* flag2p) {
  const int f = *flagp;
  const size_t nq = (size_t)n * (f ? 4 : 2) / 16;
  u32 acc = 0;
  for (size_t i = blockIdx.x * 256 + threadIdx.x; i < nq; i += (size_t)gridDim.x * 256) {
    const uint4 v = ((const uint4*)mask)[i];
    acc |= v.x | v.y | v.z | v.w;
  }
  if (__ballot(acc != 0) != 0ull && (threadIdx.x & 63) == 0)
    atomicOr(flag2p, 1);
}

// ------------------------------------------------------------- converter ---
__global__ __launch_bounds__(256) void convert_kernel(
    const void* __restrict__ src, u16* __restrict__ dst, int n, const int* __restrict__ flagp) {
  const int f = *flagp;
  const int i = (blockIdx.x * 256 + threadIdx.x) * 4;
  if (i >= n) return;
  union { uint2 u; u16 s[4]; } o;
  if (f) {
    const float4 v = *(const float4*)((const float*)src + i);
    o.s[0] = f2bf(v.x); o.s[1] = f2bf(v.y); o.s[2] = f2bf(v.z); o.s[3] = f2bf(v.w);
  } else {
    o.u = *(const uint2*)((const u16*)src + i);
  }
  *(uint2*)(dst + i) = o.u;
}

// --------------------------------------------------- RMSNorm (fused LN1) ---
__global__ __launch_bounds__(256) void rmsnorm_in_kernel(
    const void* __restrict__ xin, const u16* __restrict__ w,
    u16* __restrict__ out, u16* __restrict__ srccopy, const int* __restrict__ flagp)
{
  __shared__ float red[4];
  const int row = blockIdx.x, tid = threadIdx.x;
  const int f = *flagp;
  union { uint4 q; u16 s[8]; } uu;
  if (f) {
    const float* xr = (const float*)xin + (size_t)row * 2048 + tid * 8;
    const float4 a = *(const float4*)xr, b = *(const float4*)(xr + 4);
    const float t[8] = {a.x, a.y, a.z, a.w, b.x, b.y, b.z, b.w};
    #pragma unroll
    for (int j = 0; j < 8; j++) uu.s[j] = f2bf(t[j]);
  } else {
    uu.q = *(const uint4*)((const u16*)xin + (size_t)row * 2048 + tid * 8);
  }
  *(uint4*)(srccopy + (size_t)row * 2048 + tid * 8) = uu.q;
  float v[8];
  #pragma unroll
  for (int j = 0; j < 8; j++) v[j] = bf2f(uu.s[j]);
  float ss = 0.f;
  #pragma unroll
  for (int j = 0; j < 8; j++) ss += v[j] * v[j];
  #pragma unroll
  for (int o = 32; o; o >>= 1) ss += __shfl_xor(ss, o, 64);
  if ((tid & 63) == 0) red[tid >> 6] = ss;
  __syncthreads();
  float rstd = rsqrtf((red[0] + red[1] + red[2] + red[3]) * (1.0f / 2048.0f) + 1e-5f);
  rstd = bf2f(f2bf(rstd));
  union { uint4 q; u16 s[8]; } ww; ww.q = *(const uint4*)(w + tid * 8);
  union { uint4 q; u16 s[8]; } oo;
  #pragma unroll
  for (int j = 0; j < 8; j++) oo.s[j] = f2bf(scrub(v[j] * rstd * bf2f(ww.s[j]), 200.f));
  *(uint4*)(out + (size_t)row * 2048 + tid * 8) = oo.q;
}

// ---------------------------------------------------------------- RMSNorm ---
__global__ __launch_bounds__(256) void rmsnorm_kernel(
    const u16* __restrict__ xin, const u16* __restrict__ w, u16* __restrict__ out)
{
  __shared__ float red[4];
  const int row = blockIdx.x, tid = threadIdx.x;
  const u16* xr = xin + (size_t)row * 2048 + tid * 8;
  union { uint4 q; u16 s[8]; } uu; uu.q = *(const uint4*)xr;
  float v[8];
  #pragma unroll
  for (int j = 0; j < 8; j++) v[j] = bf2f(uu.s[j]);
  float ss = 0.f;
  #pragma unroll
  for (int j = 0; j < 8; j++) ss += v[j] * v[j];
  #pragma unroll
  for (int o = 32; o; o >>= 1) ss += __shfl_xor(ss, o, 64);
  if ((tid & 63) == 0) red[tid >> 6] = ss;
  __syncthreads();
  float rstd = rsqrtf((red[0] + red[1] + red[2] + red[3]) * (1.0f / 2048.0f) + 1e-5f);
  rstd = bf2f(f2bf(rstd));
  union { uint4 q; u16 s[8]; } ww; ww.q = *(const uint4*)(w + tid * 8);
  union { uint4 q; u16 s[8]; } oo;
  #pragma unroll
  for (int j = 0; j < 8; j++) oo.s[j] = f2bf(scrub(v[j] * rstd * bf2f(ww.s[j]), 200.f));
  *(uint4*)(out + (size_t)row * 2048 + tid * 8) = oo.q;
}

// -------------------------------------------------------------- transpose ---
__global__ __launch_bounds__(256) void transpose_kernel(
    const void* __restrict__ in, u16* __restrict__ out, int R, int C,
    const int* __restrict__ flagp)
{
  __shared__ u16 tile[32][33];
  const int f = *flagp;
  const int tx = threadIdx.x, ty = threadIdx.y;
  const int x = blockIdx.x * 32 + tx;
  const int y0 = blockIdx.y * 32;
  if (f) {
    #pragma unroll
    for (int j = ty; j < 32; j += 8) tile[j][tx] = f2bf(((const float*)in)[(size_t)(y0 + j) * C + x]);
  } else {
    #pragma unroll
    for (int j = ty; j < 32; j += 8) tile[j][tx] = ((const u16*)in)[(size_t)(y0 + j) * C + x];
  }
  __syncthreads();
  const int xo = y0 + tx, yo0 = blockIdx.x * 32;
  #pragma unroll
  for (int j = ty; j < 32; j += 8) out[(size_t)(yo0 + j) * R + xo] = tile[tx][j];
}

// ------------------------------------------------------------------- GEMM ---
// C[M,N] = A[M,K] @ Bt[N,K]^T; m97-style gload16 staging, BK=64 (half the
// barrier drains of BK=32). XCD-patch rasterization: bid&7 selects one of 8
// contiguous C-patches (2x4), bid>>3 rasterizes within (8x8 sub-tiles when
// divisible) -> per-XCD L2 working set ~8 MB with ~8x strip reuse.
enum { EPI_STORE = 0, EPI_ADD = 1, EPI_SILU = 2, EPI_ADD_OUT = 3 };

template<int EPI>
__global__ __launch_bounds__(256, 2) void gemm_bt_kernel(
    const u16* __restrict__ A, const u16* __restrict__ Bt,
    void* Cout, const void* aux, int M, int N, int K,
    int gx, int gy, const int* __restrict__ flagp)
{
  __shared__ alignas(16) u16 As[128 * 64];
  __shared__ alignas(16) u16 Bs[128 * 64];
  const int tid = threadIdx.x;
  const int wid = tid >> 6, lane = tid & 63;
  const int lrow = lane & 15, quad = lane >> 4;

  // ---- XCD-patch swizzle (bijection) ----
  int by, bx;
  const int Pr = ((gy & 1) == 0) ? 2 : 1;
  const int Pc = 8 / Pr;
  if ((gx % Pc) == 0 && (gy % Pr) == 0) {
    const int ph = gy / Pr, pw = gx / Pc;
    const int xcd = blockIdx.x & 7, local = blockIdx.x >> 3;
    const int pr = xcd / Pc, pc = xcd % Pc;
    int by_l, bx_l;
    if ((ph & 7) == 0 && (pw & 7) == 0) {
      const int t = local >> 6, u = local & 63;
      const int tpr = ph >> 3;
      const int ty = t % tpr, tx = t / tpr;
      by_l = ty * 8 + (u & 7);
      bx_l = tx * 8 + (u >> 3);
    } else {
      by_l = local % ph;
      bx_l = local / ph;
    }
    by = pr * ph + by_l;
    bx = pc * pw + bx_l;
  } else {
    by = blockIdx.x % gy;
    bx = blockIdx.x / gy;
  }
  const int m0 = by * 128, n0 = bx * 128;

  const int wm = (wid >> 1) * 64, wn = (wid & 1) * 64;

  // staging slots: 1024 16B-slots per matrix; wave w instr ii covers slots
  // (w*4+ii)*64 + lane. slot s -> row r=s>>3, pos=s&7 holds global chunk
  // gch = pos ^ (r&7) of row r.
  int arow[4], apos[4];
  #pragma unroll
  for (int ii = 0; ii < 4; ii++) {
    const int s = (wid * 4 + ii) * 64 + lane;
    arow[ii] = s >> 3;
    apos[ii] = (s & 7) ^ (arow[ii] & 7);
  }

  f32x4 acc[4][4] = {};

  for (int k0 = 0; k0 < K; k0 += 64) {
    __syncthreads();  // previous tile consumed
    #pragma unroll
    for (int ii = 0; ii < 4; ii++)
      gload16(A + (size_t)(m0 + arow[ii]) * K + k0 + apos[ii] * 8,
              &As[(wid * 4 + ii) * 512]);
    #pragma unroll
    for (int ii = 0; ii < 4; ii++)
      gload16(Bt + (size_t)(n0 + arow[ii]) * K + k0 + apos[ii] * 8,
              &Bs[(wid * 4 + ii) * 512]);
    __syncthreads();  // vmcnt(0) drained -> LDS valid

    #pragma unroll
    for (int ko = 0; ko < 2; ko++) {
      bf16x8 af[4], bfm[4];
      #pragma unroll
      for (int mt = 0; mt < 4; mt++) {
        const int r = wm + mt * 16 + lrow;
        const int p = (ko * 4 + quad) ^ (r & 7);
        af[mt] = *(const bf16x8*)&As[r * 64 + p * 8];
      }
      #pragma unroll
      for (int nt = 0; nt < 4; nt++) {
        const int r = wn + nt * 16 + lrow;
        const int p = (ko * 4 + quad) ^ (r & 7);
        bfm[nt] = *(const bf16x8*)&Bs[r * 64 + p * 8];
      }
      #pragma unroll
      for (int mt = 0; mt < 4; mt++)
        #pragma unroll
        for (int nt = 0; nt < 4; nt++)
          acc[mt][nt] = __builtin_amdgcn_mfma_f32_16x16x32_bf16(af[mt], bfm[nt], acc[mt][nt], 0, 0, 0);
    }
  }

  const int oflag = (EPI == EPI_ADD_OUT) ? *flagp : 0;
  #pragma unroll
  for (int mt = 0; mt < 4; mt++)
    #pragma unroll
    for (int nt = 0; nt < 4; nt++)
      #pragma unroll
      for (int i = 0; i < 4; i++) {
        const int row = m0 + wm + mt * 16 + quad * 4 + i;
        const int col = n0 + wn + nt * 16 + lrow;
        const size_t idx = (size_t)row * N + col;
        const float vv = acc[mt][nt][i];
        if (EPI == EPI_STORE) {
          ((u16*)Cout)[idx] = f2bf(scrub(vv, 300.f));
        } else if (EPI == EPI_ADD) {
          ((u16*)Cout)[idx] = f2bf(scrub(bf2f(((const u16*)aux)[idx]) + vv, 700.f));
        } else if (EPI == EPI_SILU) {
          float g = bf2f(((const u16*)aux)[idx]);
          g = fminf(fmaxf(g, -30.f), 30.f);
          const float s = g / (1.0f + __expf(-g));
          ((u16*)Cout)[idx] = f2bf(scrub(s * vv, 800.f));
        } else {
          const float r = scrub(bf2f(((const u16*)aux)[idx]) + vv, 1e6f);
          if (oflag) ((float*)Cout)[idx] = r;
          else       ((u16*)Cout)[idx] = f2bf(r);
        }
      }
}

// ------------------------------------------------------------------- RoPE ---
__global__ __launch_bounds__(256) void rope_kernel(
    u16* qkv, const u16* __restrict__ cosb, const u16* __restrict__ sinb)
{
  const int gw = blockIdx.x * 4 + (threadIdx.x >> 6);
  const int lane = threadIdx.x & 63;
  const int h = gw % 24;
  const int t = gw / 24;
  u16* base = qkv + (size_t)t * 4096 + h * 128;
  const u32 x01 = *(const u32*)(base + 2 * lane);
  const float x1 = bf2f((u16)(x01 & 0xffff));
  const float x2 = bf2f((u16)(x01 >> 16));
  const float c = bf2f(cosb[t * 64 + lane]);
  const float s = bf2f(sinb[t * 64 + lane]);
  const u16 o1 = f2bf(x1 * c - x2 * s);
  const u16 o2 = f2bf(x1 * s + x2 * c);
  base[lane] = o1;
  base[64 + lane] = o2;
}

// ------------------------------------------------------------ flash attn ---
#define VSTR 80
__global__ __launch_bounds__(256, 2) void flash_attn_kernel(
    const u16* __restrict__ qkv, const u16* __restrict__ vT,
    const void* __restrict__ mask, u16* __restrict__ obuf,
    const int* __restrict__ flagp, const int* __restrict__ zerop)
{
  __shared__ alignas(16) u16 Kt[64 * 128];
  __shared__ alignas(16) u16 Vt[128 * VSTR];
  __shared__ alignas(16) u16 Ps[4 * 16 * 64];

  const int qt = blockIdx.x, h = blockIdx.y, b = blockIdx.z;
  const int tid = threadIdx.x;
  const int wid = tid >> 6, lane = tid & 63;
  const int lrow = lane & 15, quad = lane >> 4;
  const int kvh = h >> 1;
  const size_t tok0 = (size_t)b * 2048;
  const int has_mask = *zerop;
  const int mf32 = *flagp;

  bf16x8 qf[4];
  {
    const u16* qptr = qkv + (tok0 + qt * 64 + wid * 16 + lrow) * 4096 + h * 128 + quad * 8;
    #pragma unroll
    for (int kk = 0; kk < 4; kk++) qf[kk] = *(const bf16x8*)(qptr + kk * 32);
  }
  const u16* kbase = qkv + tok0 * 4096 + 2048 + kvh * 128;
  const u16* vbase = vT + (size_t)(kvh * 128) * 4096 + tok0;

  float mst[4] = {-1e30f, -1e30f, -1e30f, -1e30f};
  float lst[4] = {0.f, 0.f, 0.f, 0.f};
  f32x4 oacc[8] = {};
  const float scale = 0.08838834764831845f;  // 1/sqrt(128)

  for (int kt = 0; kt < 32; kt++) {
    __syncthreads();
    #pragma unroll
    for (int ii = 0; ii < 4; ii++) {
      const int rloc = wid * 16 + ii * 4 + (lane >> 4);
      const int ch = lane & 15;
      const int gch = ch ^ (rloc & 7);
      gload16(kbase + (size_t)(kt * 64 + rloc) * 4096 + gch * 8,
              &Kt[(wid * 16 + ii * 4) * 128]);
    }
    #pragma unroll
    for (int ii = 0; ii < 4; ii++) {
      const int ci = ii * 256 + tid;
      const int d = ci >> 3, c = ci & 7;
      const int pos = c ^ (d & 7);
      const uint4 v = *(const uint4*)(vbase + (size_t)d * 4096 + kt * 64 + c * 8);
      *(uint4*)&Vt[d * VSTR + pos * 8] = v;
    }
    __syncthreads();

    f32x4 sfr[4] = {};
    #pragma unroll
    for (int nt = 0; nt < 4; nt++) {
      const int r = nt * 16 + lrow;
      #pragma unroll
      for (int kk = 0; kk < 4; kk++) {
        bf16x8 kf = *(const bf16x8*)&Kt[r * 128 + (((kk * 4 + quad) ^ (r & 7)) << 3)];
        sfr[nt] = __builtin_amdgcn_mfma_f32_16x16x32_bf16(qf[kk], kf, sfr[nt], 0, 0, 0);
      }
    }
    if (has_mask) {
      #pragma unroll
      for (int nt = 0; nt < 4; nt++)
        #pragma unroll
        for (int i = 0; i < 4; i++) {
          const size_t midx = (tok0 + qt * 64 + wid * 16 + quad * 4 + i) * 2048
                              + kt * 64 + nt * 16 + lrow;
          const float mv = mf32 ? ((const float*)mask)[midx] : bf2f(((const u16*)mask)[midx]);
          sfr[nt][i] = fminf(fmaxf(sfr[nt][i] * scale + mv, -1e4f), 1e4f);
        }
    } else {
      #pragma unroll
      for (int nt = 0; nt < 4; nt++)
        #pragma unroll
        for (int i = 0; i < 4; i++)
          sfr[nt][i] = fminf(fmaxf(sfr[nt][i] * scale, -1e4f), 1e4f);
    }
    float alpha[4], mnew[4], rsum[4];
    #pragma unroll
    for (int i = 0; i < 4; i++) {
      float mx = fmaxf(fmaxf(sfr[0][i], sfr[1][i]), fmaxf(sfr[2][i], sfr[3][i]));
      #pragma unroll
      for (int o = 8; o; o >>= 1) mx = fmaxf(mx, __shfl_xor(mx, o, 64));
      mnew[i] = fmaxf(mst[i], mx);
      alpha[i] = __expf(mst[i] - mnew[i]);
      mst[i] = mnew[i];
      rsum[i] = 0.f;
    }
    #pragma unroll
    for (int nt = 0; nt < 4; nt++)
      #pragma unroll
      for (int i = 0; i < 4; i++) {
        const float p = __expf(sfr[nt][i] - mnew[i]);
        rsum[i] += p;
        const int row = quad * 4 + i;
        const int c = nt * 2 + (lrow >> 3);
        Ps[wid * 1024 + row * 64 + ((c ^ (row & 7)) << 3) + (lrow & 7)] = f2bf(p);
      }
    #pragma unroll
    for (int i = 0; i < 4; i++) {
      #pragma unroll
      for (int o = 8; o; o >>= 1) rsum[i] += __shfl_xor(rsum[i], o, 64);
      lst[i] = lst[i] * alpha[i] + rsum[i];
    }
    #pragma unroll
    for (int dt = 0; dt < 8; dt++)
      #pragma unroll
      for (int i = 0; i < 4; i++) oacc[dt][i] *= alpha[i];

    asm volatile("s_waitcnt lgkmcnt(0)" ::: "memory");
    #pragma unroll
    for (int kk = 0; kk < 2; kk++) {
      bf16x8 pf = *(const bf16x8*)&Ps[wid * 1024 + lrow * 64 + (((kk * 4 + quad) ^ (lrow & 7)) << 3)];
      #pragma unroll
      for (int dt = 0; dt < 8; dt++) {
        const int d = dt * 16 + lrow;
        bf16x8 vf = *(const bf16x8*)&Vt[d * VSTR + (((kk * 4 + quad) ^ (d & 7)) << 3)];
        oacc[dt] = __builtin_amdgcn_mfma_f32_16x16x32_bf16(pf, vf, oacc[dt], 0, 0, 0);
      }
    }
  }

  #pragma unroll
  for (int dt = 0; dt < 8; dt++)
    #pragma unroll
    for (int i = 0; i < 4; i++) {
      const size_t tok = tok0 + qt * 64 + wid * 16 + quad * 4 + i;
      obuf[tok * 2048 + h * 128 + dt * 16 + lrow] = f2bf(scrub(oacc[dt][i] / lst[i], 500.f));
    }
}

// ----------------------------------------------------------------- launch ---
extern "C" void kernel_launch(void* const* d_in, const int* in_sizes, int n_in,
                              void* d_out, int out_size, void* d_ws, size_t ws_size,
                              hipStream_t stream) {
  (void)in_sizes; (void)n_in; (void)out_size; (void)ws_size;
  const void* hs   = d_in[0];
  const void* cosi = d_in[1];
  const void* sini = d_in[2];
  const void* mask = d_in[3];
  const void* wq   = d_in[4];
  const void* wk   = d_in[5];
  const void* wv   = d_in[6];
  const void* wo   = d_in[7];
  const void* wg   = d_in[8];
  const void* wu   = d_in[9];
  const void* wd   = d_in[10];
  const void* ln1  = d_in[11];
  const void* ln2  = d_in[12];

  char* ws = (char*)d_ws;                          // 178 MB total
  int* flag  = (int*)ws;                           // dtype flag
  int* flag2 = (int*)(ws + 64);                    // mask-nonzero flag
  u16* ln1b  = (u16*)(ws + 4096);
  u16* ln2b  = (u16*)(ws + 16384);
  u16* cosb  = (u16*)(ws + (1u << 20));
  u16* sinb  = (u16*)(ws + (1u << 20) + (1u << 19));
  u16* hsb   = (u16*)(ws + (2u  << 20));           // 16 MB bf16 hidden_states
  u16* xn    = (u16*)(ws + (18u << 20));           // 16 MB normed x; later h2
  u16* qkv   = (u16*)(ws + (34u << 20));           // 32 MB fused q|k (V unused)
  u16* abuf  = (u16*)(ws + (66u << 20));           // 16 MB attention out
  u16* wT    = (u16*)(ws + (82u << 20));           // 32 MB transposed weights
  u16* gbuf  = (u16*)(ws + (114u << 20));          // 64 MB gate/h (MLP phase)
  u16* vT    = gbuf;                               //  8 MB V^T (dead pre-MLP)
  u16* x2n   = hsb;                                // hsb dead after O-proj
  u16* h2    = xn;                                 // xn dead after QKV gemm

  dim3 tb(32, 8);
  detect_kernel<<<1, 256, 0, stream>>>((const u16*)hs, flag);
  init_flag2_kernel<<<1, 1, 0, stream>>>(flag2);
  detect_mask_kernel<<<2048, 256, 0, stream>>>(mask, 8388608, flag, flag2);
  // small converts
  convert_kernel<<<256,  256, 0, stream>>>(cosi, cosb, 262144,  flag);
  convert_kernel<<<256,  256, 0, stream>>>(sini, sinb, 262144,  flag);
  convert_kernel<<<2,    256, 0, stream>>>(ln1,  ln1b, 2048,    flag);
  convert_kernel<<<2,    256, 0, stream>>>(ln2,  ln2b, 2048,    flag);
  // LN1 fused with input conversion (writes hsb copy + xn)
  rmsnorm_in_kernel<<<4096, 256, 0, stream>>>(hs, ln1b, xn, hsb, flag);
  // weights: wq^T | wk^T | wv^T stacked as [4096][2048]
  transpose_kernel<<<dim3(64, 64), tb, 0, stream>>>(wq, wT, 2048, 2048, flag);
  transpose_kernel<<<dim3(32, 64), tb, 0, stream>>>(wk, wT + (size_t)2048 * 2048, 2048, 1024, flag);
  transpose_kernel<<<dim3(32, 64), tb, 0, stream>>>(wv, wT + (size_t)3072 * 2048, 2048, 1024, flag);
  // Q|K projection (cols 0..3071 of stride-4096 qkv) and V^T = wv^T @ xn^T
  gemm_bt_kernel<EPI_STORE><<<24 * 32, 256, 0, stream>>>(xn, wT, qkv, nullptr, 4096, 4096, 2048, 24, 32, flag);
  gemm_bt_kernel<EPI_STORE><<<32 * 8, 256, 0, stream>>>(wT + (size_t)3072 * 2048, xn, vT, nullptr, 1024, 4096, 2048, 32, 8, flag);
  // RoPE on q and k heads
  rope_kernel<<<24576, 256, 0, stream>>>(qkv, cosb, sinb);
  // attention
  flash_attn_kernel<<<dim3(32, 16, 2), 256, 0, stream>>>(qkv, vT, mask, abuf, flag, flag2);
  // O proj + residual -> h2
  transpose_kernel<<<dim3(64, 64), tb, 0, stream>>>(wo, wT, 2048, 2048, flag);
  gemm_bt_kernel<EPI_ADD><<<16 * 32, 256, 0, stream>>>(abuf, wT, h2, hsb, 4096, 2048, 2048, 16, 32, flag);
  // LN2
  rmsnorm_kernel<<<4096, 256, 0, stream>>>(h2, ln2b, x2n);
  // MLP
  transpose_kernel<<<dim3(256, 64), tb, 0, stream>>>(wg, wT, 2048, 8192, flag);
  gemm_bt_kernel<EPI_STORE><<<64 * 32, 256, 0, stream>>>(x2n, wT, gbuf, nullptr, 4096, 8192, 2048, 64, 32, flag);
  transpose_kernel<<<dim3(256, 64), tb, 0, stream>>>(wu, wT, 2048, 8192, flag);
  gemm_bt_kernel<EPI_SILU><<<64 * 32, 256, 0, stream>>>(x2n, wT, gbuf, gbuf, 4096, 8192, 2048, 64, 32, flag);
  transpose_kernel<<<dim3(64, 256), tb, 0, stream>>>(wd, wT, 8192, 2048, flag);
  gemm_bt_kernel<EPI_ADD_OUT><<<16 * 32, 256, 0, stream>>>(gbuf, wT, d_out, h2, 4096, 2048, 8192, 16, 32, flag);
}